// Round 6
// baseline (17.131 us; speedup 1.0000x reference)
//
#include <hip/hip_runtime.h>

#define D_IN  48
#define H_IN  64
#define W_IN  128
#define D_OUT 193
#define H_OUT 256
#define W_OUT 512
#define NCOL  18    // staged cols: 16 distinct w0 + 1 left-guard + 1 pair-neighbor

// 4 threads per output pixel, wave-uniform quarters of the d-range:
//   q=0: d in [0,48]   needs c[k], k in [0,12]   (d=0,1 clamp to g[0])
//   q=1: d in [49,96]  needs c[k], k in [11,24]
//   q=2: d in [97,144] needs c[k], k in [23,36]
//   q=3: d in [145,192] needs c[k], k in [35,47] (d=191,192 clamp to g[47])
// Rationale (R4 post-mortem): c[25] state put VGPR in the 65-128 band ->
// 4 waves/SIMD (occupancy quantization), same as R2 -- that, not issue rate,
// was the limiter. c[14] slices land ~48 VGPR -> 8 waves/SIMD with NO forced
// launch_bounds cap (R3's forced cap spilled 139 MB to scratch).
//
// h is block-uniform -> h-lerp folded into LDS staging (sm rows already
// h-interpolated). Softmax args within one k-segment are arithmetic in d ->
// exp values form a geometric progression: 2 exps + (len-1) muls per segment.
// Quarters merged with an exact shifted-softmax combine via LDS.

template<int Q>
__device__ __forceinline__ void compute_quarter(const float* base, float fwp,
                                                float& m_out, float& s_out, float& ds_out) {
    constexpr int K0   = (Q == 0) ? 0 : (Q == 1) ? 11 : (Q == 2) ? 23 : 35;
    constexpr int KHI  = (Q == 0) ? 11 : (Q == 1) ? 23 : (Q == 2) ? 35 : 46;
    constexpr int NC   = KHI - K0 + 2;                  // 13 or 14 c-values
    constexpr int DMIN = (Q == 0) ? 2 : (Q == 1) ? 49 : (Q == 2) ? 97 : 145;
    constexpr int DMAX = (Q == 0) ? 48 : (Q == 1) ? 96 : (Q == 2) ? 144 : 190;

    // w-lerp slice c[j] = c_global[K0+j] from h-prelerped LDS rows
    float c[NC];
    float cmin = 1e30f;
    #pragma unroll
    for (int j = 0; j < NC; ++j) {
        const float* p = base + (K0 + j) * NCOL;
        float a = p[0], b = p[1];
        float v = fmaf(fwp, b - a, a);
        c[j] = v;
        cmin = fminf(cmin, v);
    }

    // g[j] = (cmin - c[j]) * log2e  (<= 0), in place
    const float L2E = 1.4426950408889634f;
    float gb = cmin * L2E;
    #pragma unroll
    for (int j = 0; j < NC; ++j) c[j] = fmaf(c[j], -L2E, gb);

    float s0 = 0.f, s1 = 0.f, ds0 = 0.f, ds1 = 0.f;

    if (Q == 0) {             // d=0,1: fd clamps to 0 -> arg = g[0]
        float e0;
        asm("v_exp_f32 %0, %1" : "=v"(e0) : "v"(c[0]));
        s0 = e0 + e0;
        ds0 = e0;             // 0*e + 1*e
    }

    // main segments: df(d) = (96d-145)/386; segment k covers
    // d in [ceil((386k+145)/96), ceil((386(k+1)+145)/96)-1], clamped to quarter
    #pragma unroll
    for (int k = K0; k <= KHI; ++k) {
        int dlo = (386 * k + 240) / 96;           if (dlo < DMIN) dlo = DMIN;
        int dhi = (386 * (k + 1) + 240) / 96 - 1; if (dhi > DMAX) dhi = DMAX;
        int j0 = k - K0;
        float delta = c[j0 + 1] - c[j0];
        float f0 = (float)(96 * dlo - 145 - 386 * k) * (1.0f / 386.0f);  // const
        float arg0 = fmaf(f0, delta, c[j0]);
        float e, r;
        asm("v_exp_f32 %0, %1" : "=v"(e) : "v"(arg0));
        float rarg = delta * (96.0f / 386.0f);
        asm("v_exp_f32 %0, %1" : "=v"(r) : "v"(rarg));
        #pragma unroll
        for (int u = 0; u < 5; ++u) {             // max segment length 5
            int d = dlo + u;
            if (d <= dhi) {
                if (d & 1) { s1 += e; ds1 = fmaf((float)d, e, ds1); }
                else       { s0 += e; ds0 = fmaf((float)d, e, ds0); }
                e *= r;
            }
        }
    }

    if (Q == 3) {             // d=191,192: k0 clamps to 47 -> arg = g[47]
        float e;
        asm("v_exp_f32 %0, %1" : "=v"(e) : "v"(c[NC - 1]));
        s0 += e + e;
        ds0 = fmaf(383.f, e, ds0);   // 191*e + 192*e
    }

    m_out  = cmin;
    s_out  = (s0 + s1);
    ds_out = (ds0 + ds1);
}

__global__ __launch_bounds__(256) void disp_kernel(const float* __restrict__ x,
                                                   float* __restrict__ out) {
    __shared__ float sm[D_IN * NCOL];                      // 3456 B, h-prelerped
    __shared__ float red_m[256], red_s[256], red_d[256];   // 3 KB merge buffers

    int t = threadIdx.x;
    int i = t & 63;                          // pixel index within block
    int p0 = blockIdx.x << 6;                // first pixel of block (64/block)
    int p = p0 + i;
    int w = p & (W_OUT - 1);
    int h = (p >> 9) & (H_OUT - 1);          // uniform within block
    int b = p >> 17;                          // uniform
    int wblk = p0 & (W_OUT - 1);

    // --- h interpolation (uniform; half-pixel, clamp as pair+frac) ---
    float hf = (h + 0.5f) * 0.25f - 0.5f;
    float hfl = floorf(hf);
    int h0 = (int)hfl;
    float fh = hf - hfl;
    int hp; float fhp;
    if (h0 < 0)              { hp = 0;        fhp = 0.f; }
    else if (h0 >= H_IN - 1) { hp = H_IN - 2; fhp = 1.f; }
    else                     { hp = h0;       fhp = fh;  }

    // --- w interpolation ---
    float wf = (w + 0.5f) * 0.25f - 0.5f;
    float wfl = floorf(wf);
    int w0 = (int)wfl;
    float fw = wf - wfl;
    int wp; float fwp;
    if (w0 < 0)              { wp = 0;        fwp = 0.f; }
    else if (w0 >= W_IN - 1) { wp = W_IN - 2; fwp = 1.f; }
    else                     { wp = w0;       fwp = fw;  }

    // --- cooperative staging with fused h-lerp:
    //     sm[k][j] = lerp(x[b][k][hp][col], x[b][k][hp+1][col], fhp) ---
    int col0 = (wblk >> 2) - 1; if (col0 < 0) col0 = 0;
    const float* xrow = x + (size_t)b * (D_IN * H_IN * W_IN) + hp * W_IN;
    for (int idx = t; idx < D_IN * NCOL; idx += 256) {
        int k = idx / NCOL;
        int j = idx - k * NCOL;
        int col = col0 + j; if (col > W_IN - 1) col = W_IN - 1;
        const float* q = xrow + k * (H_IN * W_IN) + col;
        float a = q[0], bq = q[W_IN];
        sm[idx] = fmaf(fhp, bq - a, a);
    }
    __syncthreads();

    const float* base = &sm[wp - col0];
    float m, S, D;
    int q = t >> 6;
    if      (q == 0) compute_quarter<0>(base, fwp, m, S, D);
    else if (q == 1) compute_quarter<1>(base, fwp, m, S, D);
    else if (q == 2) compute_quarter<2>(base, fwp, m, S, D);
    else             compute_quarter<3>(base, fwp, m, S, D);

    red_m[t] = m; red_s[t] = S; red_d[t] = D;
    __syncthreads();

    if (t < 64) {
        float m0 = red_m[t],       s0 = red_s[t],       d0 = red_d[t];
        float m1 = red_m[t + 64],  s1 = red_s[t + 64],  d1 = red_d[t + 64];
        float m2 = red_m[t + 128], s2 = red_s[t + 128], d2 = red_d[t + 128];
        float m3 = red_m[t + 192], s3 = red_s[t + 192], d3 = red_d[t + 192];
        const float L2E = 1.4426950408889634f;
        float mu = fminf(fminf(m0, m1), fminf(m2, m3));
        float f0, f1, f2, f3;
        float a0 = (mu - m0) * L2E, a1 = (mu - m1) * L2E;
        float a2 = (mu - m2) * L2E, a3 = (mu - m3) * L2E;
        asm("v_exp_f32 %0, %1" : "=v"(f0) : "v"(a0));
        asm("v_exp_f32 %0, %1" : "=v"(f1) : "v"(a1));
        asm("v_exp_f32 %0, %1" : "=v"(f2) : "v"(a2));
        asm("v_exp_f32 %0, %1" : "=v"(f3) : "v"(a3));
        float num = (d0 * f0 + d1 * f1) + (d2 * f2 + d3 * f3);
        float den = (s0 * f0 + s1 * f1) + (s2 * f2 + s3 * f3);
        out[p] = num / den;
    }
}

extern "C" void kernel_launch(void* const* d_in, const int* in_sizes, int n_in,
                              void* d_out, int out_size, void* d_ws, size_t ws_size,
                              hipStream_t stream) {
    const float* x = (const float*)d_in[0];
    float* out = (float*)d_out;
    int total_pixels = 2 * H_OUT * W_OUT;      // 262144
    int blocks = total_pixels / 64;            // 4096 (4 threads/pixel)
    disp_kernel<<<blocks, 256, 0, stream>>>(x, out);
}